// Round 3
// baseline (3466.324 us; speedup 1.0000x reference)
//
#include <hip/hip_runtime.h>
#include <math.h>

#define SS 512
#define AANG 60
#define DDET 729
#define NPIX (SS*SS)        // 262144
#define NSIN (AANG*DDET)    // 43740
#define NTAPS 1457

typedef float v2f __attribute__((ext_vector_type(2)));

// ---------------- trig table: ca[60], sa[60] ----------------
__global__ void trig_kernel(const float* __restrict__ theta, float* __restrict__ trig){
  int a = threadIdx.x;
  if (a < AANG){ trig[a] = cosf(theta[a]); trig[AANG+a] = sinf(theta[a]); }
}

// ---------------- ramp-filter taps (exact irfft of 2*rfftfreq(2048), folded pi/120) --------
__global__ void taps_kernel(float* __restrict__ taps){
  __shared__ double red[256];
  int m  = blockIdx.x;      // 0..1456
  int mm = m - 728;         // -728..728
  double s = 0.0;
  for (int k = 1 + (int)threadIdx.x; k <= 1023; k += 256){
    int phase = (k*mm) & 2047;   // exact integer mod 2048 (works for negative)
    s += (double)k * cos((double)phase * (M_PI/1024.0));
  }
  red[threadIdx.x] = s;
  __syncthreads();
  for (int off=128; off; off>>=1){
    if ((int)threadIdx.x < off) red[threadIdx.x] += red[threadIdx.x+off];
    __syncthreads();
  }
  if (threadIdx.x==0){
    double x = (red[0]*(1.0/512.0) + ((mm & 1) ? -1.0 : 1.0)) / 2048.0;
    taps[m] = (float)(x * (M_PI/120.0));   // fold FBP normalization pi/(2*60)
  }
}

// ---------------- all six weight transposes in ONE dispatch ----------------
// [L][Cout][Cin][3][3] -> [L][Cin][9][Cout]
__global__ void transpose_all(const float* __restrict__ s0, float* __restrict__ d0,
                              const float* __restrict__ s1, float* __restrict__ d1,
                              const float* __restrict__ s2, float* __restrict__ d2,
                              const float* __restrict__ s3, float* __restrict__ d3,
                              const float* __restrict__ s4, float* __restrict__ d4,
                              const float* __restrict__ s5, float* __restrict__ d5){
  int idx = blockIdx.x*256 + (int)threadIdx.x;
  const float* src; float* dst; int Cout, Cin;
  if      (idx < 20160){                src=s0; dst=d0; Cout=32; Cin=7; }
  else if (idx < 112320){ idx-=20160;   src=s1; dst=d1; Cout=32; Cin=32; }
  else if (idx < 126720){ idx-=112320;  src=s2; dst=d2; Cout=5;  Cin=32; }
  else if (idx < 144000){ idx-=126720;  src=s3; dst=d3; Cout=32; Cin=6; }
  else if (idx < 236160){ idx-=144000;  src=s4; dst=d4; Cout=32; Cin=32; }
  else if (idx < 250560){ idx-=236160;  src=s5; dst=d5; Cout=5;  Cin=32; }
  else return;
  int t = idx % 9; int r = idx/9;
  int i = r % Cin; r /= Cin;
  int o = r % Cout; int l = r/Cout;
  dst[((l*Cin+i)*9+t)*Cout+o] = src[idx];
}

// ---------------- radon forward with support clipping + transpose choice ----------------
__device__ inline void clipr(float al, float be, float lo, float hi,
                             float& A, float& B, bool& empty){
  if (fabsf(al) < 1e-7f){ if (be < lo || be > hi) empty = true; return; }
  float t0 = (lo - be)/al, t1 = (hi - be)/al;
  float mn = fminf(t0,t1), mx = fmaxf(t0,t1);
  A = fmaxf(A, mn); B = fminf(B, mx);
}

__device__ inline float samp_guard(const float* __restrict__ base, float aR, float bR,
                                   float aC, float bC, int t){
  float tp = (float)t - 255.5f;
  float R = fmaf(aR, tp, bR);
  float C = fmaf(aC, tp, bC);
  float rf = floorf(R), cf = floorf(C);
  int r0 = (int)rf, c0 = (int)cf;
  int r1 = r0+1,    c1 = c0+1;
  float fr = R - rf, fc = C - cf;
  bool r0ok = (r0>=0 && r0<SS), r1ok = (r1>=0 && r1<SS);
  bool c0ok = (c0>=0 && c0<SS), c1ok = (c1>=0 && c1<SS);
  float v00 = (r0ok && c0ok) ? base[r0*SS+c0] : 0.f;
  float v01 = (r0ok && c1ok) ? base[r0*SS+c1] : 0.f;
  float v10 = (r1ok && c0ok) ? base[r1*SS+c0] : 0.f;
  float v11 = (r1ok && c1ok) ? base[r1*SS+c1] : 0.f;
  return (1.f-fr)*((1.f-fc)*v00 + fc*v01) + fr*((1.f-fc)*v10 + fc*v11);
}

__global__ __launch_bounds__(256) void radon_fwd_kernel(
    const float* __restrict__ img, const float* __restrict__ imgT,
    const float* __restrict__ trig, float* __restrict__ out){
  int gid  = blockIdx.x*4 + ((int)threadIdx.x >> 6);
  int lane = (int)threadIdx.x & 63;
  if (gid >= NSIN) return;
  int a = gid / DDET;
  int d = gid - a*DDET;
  float ca = trig[a], sa = trig[AANG+a];
  float sd = (float)d - 364.0f;
  // img sample: row = ca*tp + Rc ; col = -sa*tp + Cc   (tp = t - 255.5)
  float Rc = fmaf(sd, sa, 255.5f);
  float Cc = fmaf(sd, ca, 255.5f);
  float aR = ca, bR = Rc, aC = -sa, bC = Cc;
  const float* base = img;
  if (fabsf(ca) > fabsf(sa)){  // transposed image: rows vary by |sa| < |ca| per t
    base = imgT;
    float tmp;
    tmp=aR; aR=aC; aC=tmp;
    tmp=bR; bR=bC; bC=tmp;
  }
  // wave-uniform t-ranges (tp units)
  float tiA = -255.5f, tiB = 255.5f;  bool iE=false;   // strict interior
  float teA = -255.5f, teB = 255.5f;  bool eE=false;   // any contribution
  clipr(aR,bR, 0.001f, 510.999f, tiA,tiB,iE);
  clipr(aC,bC, 0.001f, 510.999f, tiA,tiB,iE);
  clipr(aR,bR, -0.999f, 511.999f, teA,teB,eE);
  clipr(aC,bC, -0.999f, 511.999f, teA,teB,eE);
  float acc = 0.f;
  if (!eE && teA <= teB){
    int eA = max(0,   (int)floorf(teA+255.5f) - 1);
    int eB = min(511, (int)ceilf (teB+255.5f) + 1);
    int iA = (int)ceilf (tiA+255.5f) + 1;
    int iB = (int)floorf(tiB+255.5f) - 1;
    iA = max(iA, eA); iB = min(iB, eB);
    if (iE || iA > iB){
      for (int t = eA+lane; t <= eB; t += 64) acc += samp_guard(base,aR,bR,aC,bC,t);
    } else {
      for (int t = eA+lane;   t <  iA; t += 64) acc += samp_guard(base,aR,bR,aC,bC,t);
      for (int t = iB+1+lane; t <= eB; t += 64) acc += samp_guard(base,aR,bR,aC,bC,t);
      for (int t = iA+lane;   t <= iB; t += 64){
        float tp = (float)t - 255.5f;
        float R = fmaf(aR, tp, bR);
        float C = fmaf(aC, tp, bC);
        int r0 = (int)R, c0 = (int)C;        // R,C >= 0 -> trunc == floor
        float fr = R - (float)r0, fc = C - (float)c0;
        const float* p = base + r0*SS + c0;
        float v00 = p[0], v01 = p[1], v10 = p[SS], v11 = p[SS+1];
        float top = v00 + fc*(v01-v00);
        float bot = v10 + fc*(v11-v10);
        acc += top + fr*(bot-top);
      }
    }
  }
  for (int off=32; off; off>>=1) acc += __shfl_down(acc, off);
  if (lane==0) out[gid] = acc;
}

// ---------------- ramp filter: direct 1457-tap conv along detector axis ----------------
__global__ void filter_kernel(const float* __restrict__ h0, const float* __restrict__ taps,
                              float* __restrict__ h1){
  int gid = blockIdx.x*blockDim.x + threadIdx.x;
  if (gid >= NSIN) return;
  int a = gid / DDET;
  int j = gid - a*DDET;
  const float* row = h0 + a*DDET;
  float acc = 0.f;
  for (int k=0;k<DDET;k++){
    acc += row[k] * taps[728 + j - k];
  }
  h1[gid] = acc;
}

// ---------------- backprojection with LDS-staged detector windows ----------------
__global__ __launch_bounds__(256) void backproj_kernel(
    const float* __restrict__ h1, const float* __restrict__ trig,
    float* __restrict__ out){
  __shared__ float sh[AANG*28];
  __shared__ int   sbase[AANG];
  __shared__ float strig[2*AANG];
  int tid = threadIdx.x;
  int x0 = (blockIdx.x & 31) * 16, y0 = (blockIdx.x >> 5) * 16;
  if (tid < 2*AANG) strig[tid] = trig[tid];
  __syncthreads();
  if (tid < AANG){
    float ca = strig[tid], sa = strig[AANG+tid];
    float Xa = (float)x0 - 255.5f, Xb = Xa + 15.f;
    float Ya = (float)y0 - 255.5f, Yb = Ya + 15.f;
    float s00 = Xa*ca + Ya*sa, s01 = Xb*ca + Ya*sa;
    float s10 = Xa*ca + Yb*sa, s11 = Xb*ca + Yb*sa;
    float mn = fminf(fminf(s00,s01), fminf(s10,s11)) + 364.0f;
    sbase[tid] = (int)floorf(mn) - 2;
  }
  __syncthreads();
  for (int s = tid; s < AANG*28; s += 256){
    int a = s / 28, j = s - a*28;
    int idx = sbase[a] + j;
    sh[s] = (idx >= 0 && idx < DDET) ? h1[a*DDET + idx] : 0.f;
  }
  __syncthreads();
  int x = x0 + (tid & 15), y = y0 + (tid >> 4);
  float X = (float)x - 255.5f, Y = (float)y - 255.5f;
  float acc = 0.f;
  #pragma unroll 6
  for (int a=0;a<AANG;a++){
    float sidx = fmaf(X, strig[a], fmaf(Y, strig[AANG+a], 364.0f));
    float ff = floorf(sidx);
    int k = (int)ff - sbase[a];
    float fi = sidx - ff;
    float v0 = sh[a*28+k], v1 = sh[a*28+k+1];
    acc += v0 + fi*(v1-v0);
  }
  out[y*SS+x] = acc;
}

// ---------------- fast 3x3 SAME conv (packed-fp32 FMA for even COUT) ----------------
template<int COUT, int W>
__global__ __launch_bounds__(256) void conv3x3_fast(
    const float* __restrict__ in1, int Cin1,
    const float* __restrict__ in2, int Cin2,
    const float* __restrict__ wt,
    const float* __restrict__ bias, const float* __restrict__ prelu,
    float* __restrict__ out, int H, int accum,
    float* __restrict__ fout, float* __restrict__ tout)
{
  int HW = H*W;
  int pix = blockIdx.x*256 + (int)threadIdx.x;
  if (pix >= HW) return;
  int y = pix / W, x = pix - y*W;
  bool ym = y>0, yp = y<H-1, xm = x>0, xp = x<W-1;

  if constexpr ((COUT & 1) == 0){
    v2f acc[COUT/2];
    #pragma unroll
    for (int o=0;o<COUT/2;o++) acc[o] = v2f{bias[2*o], bias[2*o+1]};
    const float* wr = wt;
    for (int part=0; part<2; part++){
      const float* src = part ? in2 : in1;
      int nch = part ? Cin2 : Cin1;
      const float* ip = src + pix;
      for (int i=0;i<nch;i++, ip+=HW){
        float p4 = ip[0];
        float p0=0,p1=0,p2=0,p3=0,p5=0,p6=0,p7=0,p8=0;
        if (ym){ p1 = ip[-W]; if (xm) p0 = ip[-W-1]; if (xp) p2 = ip[-W+1]; }
        if (xm) p3 = ip[-1];
        if (xp) p5 = ip[1];
        if (yp){ p7 = ip[W]; if (xm) p6 = ip[W-1]; if (xp) p8 = ip[W+1]; }
        float p[9] = {p0,p1,p2,p3,p4,p5,p6,p7,p8};
        #pragma unroll
        for (int t=0;t<9;t++){
          v2f vv = { p[t], p[t] };
          const v2f* w2 = (const v2f*)(wr + t*COUT);
          #pragma unroll
          for (int o=0;o<COUT/2;o++)
            acc[o] = __builtin_elementwise_fma(vv, w2[o], acc[o]);
        }
        wr += 9*COUT;
      }
    }
    float aa = prelu ? *prelu : 0.f;
    float* op = out + pix;
    #pragma unroll
    for (int o=0;o<COUT;o++){
      float s = (o&1) ? acc[o>>1].y : acc[o>>1].x;
      if (prelu) s = (s>=0.f) ? s : aa*s;
      if (accum) s += op[o*HW];
      op[o*HW] = s;
    }
  } else {
    float acc[COUT];
    #pragma unroll
    for (int o=0;o<COUT;o++) acc[o] = bias[o];
    const float* wr = wt;
    for (int part=0; part<2; part++){
      const float* src = part ? in2 : in1;
      int nch = part ? Cin2 : Cin1;
      const float* ip = src + pix;
      for (int i=0;i<nch;i++, ip+=HW){
        float p4 = ip[0];
        float p0=0,p1=0,p2=0,p3=0,p5=0,p6=0,p7=0,p8=0;
        if (ym){ p1 = ip[-W]; if (xm) p0 = ip[-W-1]; if (xp) p2 = ip[-W+1]; }
        if (xm) p3 = ip[-1];
        if (xp) p5 = ip[1];
        if (yp){ p7 = ip[W]; if (xm) p6 = ip[W-1]; if (xp) p8 = ip[W+1]; }
        float p[9] = {p0,p1,p2,p3,p4,p5,p6,p7,p8};
        #pragma unroll
        for (int t=0;t<9;t++){
          float v = p[t];
          #pragma unroll
          for (int o=0;o<COUT;o++) acc[o] += v * wr[t*COUT+o];
        }
        wr += 9*COUT;
      }
    }
    float aa = prelu ? *prelu : 0.f;
    float* op = out + pix;
    #pragma unroll
    for (int o=0;o<COUT;o++){
      float s = acc[o];
      if (prelu) s = (s>=0.f) ? s : aa*s;
      if (accum) s += op[o*HW];
      op[o*HW] = s;
      if (o==1 && tout) tout[x*W + y] = s;                       // transposed f[ch1] (square only)
      if (o==0 && fout){ fout[pix]=s; fout[HW+pix]=s; fout[2*HW+pix]=s; }
    }
  }
}

extern "C" void kernel_launch(void* const* d_in, const int* in_sizes, int n_in,
                              void* d_out, int out_size, void* d_ws, size_t ws_size,
                              hipStream_t stream){
  const float* g     = (const float*)d_in[2];
  const float* theta = (const float*)d_in[3];
  const float* dw1 = (const float*)d_in[5];
  const float* db1 = (const float*)d_in[6];
  const float* da1 = (const float*)d_in[7];
  const float* dw2 = (const float*)d_in[8];
  const float* db2 = (const float*)d_in[9];
  const float* da2 = (const float*)d_in[10];
  const float* dw3 = (const float*)d_in[11];
  const float* db3 = (const float*)d_in[12];
  const float* pw1 = (const float*)d_in[13];
  const float* pb1 = (const float*)d_in[14];
  const float* pa1 = (const float*)d_in[15];
  const float* pw2 = (const float*)d_in[16];
  const float* pb2 = (const float*)d_in[17];
  const float* pa2 = (const float*)d_in[18];
  const float* pw3 = (const float*)d_in[19];
  const float* pb3 = (const float*)d_in[20];

  float* ws     = (float*)d_ws;
  float* trig   = ws;                  // 128
  float* taps   = ws + 128;            // 1457 (region to 2048)
  float* h      = ws + 2048;           // 5*NSIN
  float* f      = h + 5*NSIN;          // 5*NPIX
  float* imgT   = f + 5*NPIX;          // NPIX  (transpose of f[ch1])
  float* bp     = imgT + NPIX;         // NPIX
  float* dx     = bp + NPIX;           // 2*NSIN  (opf | g copy, contiguous)
  float* opf    = dx;
  float* gcopy  = dx + NSIN;
  float* h1     = dx + 2*NSIN;         // NSIN
  float* primT1 = h1 + NSIN;           // 32*NPIX
  float* primT2 = primT1 + 32*NPIX;    // 32*NPIX
  float* dualT1 = primT1;              // aliased, lifetimes disjoint
  float* dualT2 = dualT1 + 32*NSIN;
  float* wsp  = primT2 + 32*NPIX;
  float* wtd1 = wsp;                   // 20160
  float* wtd2 = wsp + 20160;           // 92160
  float* wtd3 = wsp + 112320;          // 14400
  float* wtp1 = wsp + 126720;          // 17280
  float* wtp2 = wsp + 144000;          // 92160
  float* wtp3 = wsp + 236160;          // 14400

  // zero h, f, imgT (contiguous)
  hipMemsetAsync(h, 0, (size_t)(5*NSIN + 5*NPIX + NPIX)*sizeof(float), stream);
  hipMemcpyAsync(gcopy, g, (size_t)NSIN*sizeof(float), hipMemcpyDeviceToDevice, stream);
  trig_kernel<<<1,64,0,stream>>>(theta, trig);
  taps_kernel<<<NTAPS,256,0,stream>>>(taps);
  transpose_all<<<(250560+255)/256,256,0,stream>>>(dw1,wtd1, dw2,wtd2, dw3,wtd3,
                                                   pw1,wtp1, pw2,wtp2, pw3,wtp3);

  const int GD = (NSIN+255)/256;   // 171
  const int GP = NPIX/256;         // 1024

  for (int i=0;i<10;i++){
    radon_fwd_kernel<<<(NSIN+3)/4,256,0,stream>>>(f + NPIX, imgT, trig, opf);
    // dual block: in = [h(5) | opf(1) g(1)]
    conv3x3_fast<32,DDET><<<GD,256,0,stream>>>(h, 5, dx, 2,          wtd1+i*7*9*32,  db1+(size_t)i*32, da1+i, dualT1, AANG, 0, nullptr, nullptr);
    conv3x3_fast<32,DDET><<<GD,256,0,stream>>>(dualT1, 32, nullptr, 0, wtd2+i*32*9*32, db2+(size_t)i*32, da2+i, dualT2, AANG, 0, nullptr, nullptr);
    conv3x3_fast<5,DDET><<<GD,256,0,stream>>>(dualT2, 32, nullptr, 0,  wtd3+i*32*9*5,  db3+(size_t)i*5,  nullptr, h, AANG, 1, nullptr, nullptr);
    filter_kernel<<<GD,256,0,stream>>>(h, taps, h1);
    backproj_kernel<<<GP,256,0,stream>>>(h1, trig, bp);
    // primal block: in = [f(5) | bp(1)]
    conv3x3_fast<32,SS><<<GP,256,0,stream>>>(f, 5, bp, 1,            wtp1+i*6*9*32,  pb1+(size_t)i*32, pa1+i, primT1, SS, 0, nullptr, nullptr);
    conv3x3_fast<32,SS><<<GP,256,0,stream>>>(primT1, 32, nullptr, 0,  wtp2+i*32*9*32, pb2+(size_t)i*32, pa2+i, primT2, SS, 0, nullptr, nullptr);
    conv3x3_fast<5,SS><<<GP,256,0,stream>>>(primT2, 32, nullptr, 0,   wtp3+i*32*9*5,  pb3+(size_t)i*5,  nullptr, f, SS, 1,
                                            (i==9) ? (float*)d_out : nullptr, imgT);
  }
}

// Round 4
// 3086.229 us; speedup vs baseline: 1.1232x; 1.1232x over previous
//
#include <hip/hip_runtime.h>
#include <math.h>

#define SS 512
#define AANG 60
#define DDET 729
#define NPIX (SS*SS)        // 262144
#define NSIN (AANG*DDET)    // 43740
#define NTAPS 1457

typedef float v4u __attribute__((ext_vector_type(4), aligned(4)));
typedef float v2u __attribute__((ext_vector_type(2), aligned(8)));

// ---------------- trig table: ca[60], sa[60] ----------------
__global__ void trig_kernel(const float* __restrict__ theta, float* __restrict__ trig){
  int a = threadIdx.x;
  if (a < AANG){ trig[a] = cosf(theta[a]); trig[AANG+a] = sinf(theta[a]); }
}

// ---------------- ramp-filter taps (exact irfft of 2*rfftfreq(2048), folded pi/120) --------
__global__ void taps_kernel(float* __restrict__ taps){
  __shared__ double red[256];
  int m  = blockIdx.x;      // 0..1456
  int mm = m - 728;         // -728..728
  double s = 0.0;
  for (int k = 1 + (int)threadIdx.x; k <= 1023; k += 256){
    int phase = (k*mm) & 2047;   // exact integer mod 2048 (works for negative)
    s += (double)k * cos((double)phase * (M_PI/1024.0));
  }
  red[threadIdx.x] = s;
  __syncthreads();
  for (int off=128; off; off>>=1){
    if ((int)threadIdx.x < off) red[threadIdx.x] += red[threadIdx.x+off];
    __syncthreads();
  }
  if (threadIdx.x==0){
    double x = (red[0]*(1.0/512.0) + ((mm & 1) ? -1.0 : 1.0)) / 2048.0;
    taps[m] = (float)(x * (M_PI/120.0));   // fold FBP normalization pi/(2*60)
  }
}

// ---------------- all six weight transposes in ONE dispatch ----------------
// [L][Cout][Cin][3][3] -> [L][Cin][9][Cout]
__global__ void transpose_all(const float* __restrict__ s0, float* __restrict__ d0,
                              const float* __restrict__ s1, float* __restrict__ d1,
                              const float* __restrict__ s2, float* __restrict__ d2,
                              const float* __restrict__ s3, float* __restrict__ d3,
                              const float* __restrict__ s4, float* __restrict__ d4,
                              const float* __restrict__ s5, float* __restrict__ d5){
  int idx = blockIdx.x*256 + (int)threadIdx.x;
  const float* src; float* dst; int Cout, Cin;
  if      (idx < 20160){                src=s0; dst=d0; Cout=32; Cin=7; }
  else if (idx < 112320){ idx-=20160;   src=s1; dst=d1; Cout=32; Cin=32; }
  else if (idx < 126720){ idx-=112320;  src=s2; dst=d2; Cout=5;  Cin=32; }
  else if (idx < 144000){ idx-=126720;  src=s3; dst=d3; Cout=32; Cin=6; }
  else if (idx < 236160){ idx-=144000;  src=s4; dst=d4; Cout=32; Cin=32; }
  else if (idx < 250560){ idx-=236160;  src=s5; dst=d5; Cout=5;  Cin=32; }
  else return;
  int t = idx % 9; int r = idx/9;
  int i = r % Cin; r /= Cin;
  int o = r % Cout; int l = r/Cout;
  dst[((l*Cin+i)*9+t)*Cout+o] = src[idx];
}

// ---------------- radon forward with support clipping + transpose choice ----------------
__device__ inline void clipr(float al, float be, float lo, float hi,
                             float& A, float& B, bool& empty){
  if (fabsf(al) < 1e-7f){ if (be < lo || be > hi) empty = true; return; }
  float t0 = (lo - be)/al, t1 = (hi - be)/al;
  float mn = fminf(t0,t1), mx = fmaxf(t0,t1);
  A = fmaxf(A, mn); B = fminf(B, mx);
}

__device__ inline float samp_guard(const float* __restrict__ base, float aR, float bR,
                                   float aC, float bC, int t){
  float tp = (float)t - 255.5f;
  float R = fmaf(aR, tp, bR);
  float C = fmaf(aC, tp, bC);
  float rf = floorf(R), cf = floorf(C);
  int r0 = (int)rf, c0 = (int)cf;
  int r1 = r0+1,    c1 = c0+1;
  float fr = R - rf, fc = C - cf;
  bool r0ok = (r0>=0 && r0<SS), r1ok = (r1>=0 && r1<SS);
  bool c0ok = (c0>=0 && c0<SS), c1ok = (c1>=0 && c1<SS);
  float v00 = (r0ok && c0ok) ? base[r0*SS+c0] : 0.f;
  float v01 = (r0ok && c1ok) ? base[r0*SS+c1] : 0.f;
  float v10 = (r1ok && c0ok) ? base[r1*SS+c0] : 0.f;
  float v11 = (r1ok && c1ok) ? base[r1*SS+c1] : 0.f;
  return (1.f-fr)*((1.f-fc)*v00 + fc*v01) + fr*((1.f-fc)*v10 + fc*v11);
}

__global__ __launch_bounds__(256) void radon_fwd_kernel(
    const float* __restrict__ img, const float* __restrict__ imgT,
    const float* __restrict__ trig, float* __restrict__ out){
  int gid  = blockIdx.x*4 + ((int)threadIdx.x >> 6);
  int lane = (int)threadIdx.x & 63;
  if (gid >= NSIN) return;
  int a = gid / DDET;
  int d = gid - a*DDET;
  float ca = trig[a], sa = trig[AANG+a];
  float sd = (float)d - 364.0f;
  float Rc = fmaf(sd, sa, 255.5f);
  float Cc = fmaf(sd, ca, 255.5f);
  float aR = ca, bR = Rc, aC = -sa, bC = Cc;
  const float* base = img;
  if (fabsf(ca) > fabsf(sa)){
    base = imgT;
    float tmp;
    tmp=aR; aR=aC; aC=tmp;
    tmp=bR; bR=bC; bC=tmp;
  }
  float tiA = -255.5f, tiB = 255.5f;  bool iE=false;
  float teA = -255.5f, teB = 255.5f;  bool eE=false;
  clipr(aR,bR, 0.001f, 510.999f, tiA,tiB,iE);
  clipr(aC,bC, 0.001f, 510.999f, tiA,tiB,iE);
  clipr(aR,bR, -0.999f, 511.999f, teA,teB,eE);
  clipr(aC,bC, -0.999f, 511.999f, teA,teB,eE);
  float acc = 0.f;
  if (!eE && teA <= teB){
    int eA = max(0,   (int)floorf(teA+255.5f) - 1);
    int eB = min(511, (int)ceilf (teB+255.5f) + 1);
    int iA = (int)ceilf (tiA+255.5f) + 1;
    int iB = (int)floorf(tiB+255.5f) - 1;
    iA = max(iA, eA); iB = min(iB, eB);
    if (iE || iA > iB){
      for (int t = eA+lane; t <= eB; t += 64) acc += samp_guard(base,aR,bR,aC,bC,t);
    } else {
      for (int t = eA+lane;   t <  iA; t += 64) acc += samp_guard(base,aR,bR,aC,bC,t);
      for (int t = iB+1+lane; t <= eB; t += 64) acc += samp_guard(base,aR,bR,aC,bC,t);
      for (int t = iA+lane;   t <= iB; t += 64){
        float tp = (float)t - 255.5f;
        float R = fmaf(aR, tp, bR);
        float C = fmaf(aC, tp, bC);
        int r0 = (int)R, c0 = (int)C;
        float fr = R - (float)r0, fc = C - (float)c0;
        const float* p = base + r0*SS + c0;
        float v00 = p[0], v01 = p[1], v10 = p[SS], v11 = p[SS+1];
        float top = v00 + fc*(v01-v00);
        float bot = v10 + fc*(v11-v10);
        acc += top + fr*(bot-top);
      }
    }
  }
  for (int off=32; off; off>>=1) acc += __shfl_down(acc, off);
  if (lane==0) out[gid] = acc;
}

// ---------------- ramp filter: direct 1457-tap conv along detector axis ----------------
__global__ void filter_kernel(const float* __restrict__ h0, const float* __restrict__ taps,
                              float* __restrict__ h1){
  int gid = blockIdx.x*blockDim.x + threadIdx.x;
  if (gid >= NSIN) return;
  int a = gid / DDET;
  int j = gid - a*DDET;
  const float* row = h0 + a*DDET;
  float acc = 0.f;
  for (int k=0;k<DDET;k++){
    acc += row[k] * taps[728 + j - k];
  }
  h1[gid] = acc;
}

// ---------------- backprojection with LDS-staged detector windows ----------------
__global__ __launch_bounds__(256) void backproj_kernel(
    const float* __restrict__ h1, const float* __restrict__ trig,
    float* __restrict__ out){
  __shared__ float sh[AANG*28];
  __shared__ int   sbase[AANG];
  __shared__ float strig[2*AANG];
  int tid = threadIdx.x;
  int x0 = (blockIdx.x & 31) * 16, y0 = (blockIdx.x >> 5) * 16;
  if (tid < 2*AANG) strig[tid] = trig[tid];
  __syncthreads();
  if (tid < AANG){
    float ca = strig[tid], sa = strig[AANG+tid];
    float Xa = (float)x0 - 255.5f, Xb = Xa + 15.f;
    float Ya = (float)y0 - 255.5f, Yb = Ya + 15.f;
    float s00 = Xa*ca + Ya*sa, s01 = Xb*ca + Ya*sa;
    float s10 = Xa*ca + Yb*sa, s11 = Xb*ca + Yb*sa;
    float mn = fminf(fminf(s00,s01), fminf(s10,s11)) + 364.0f;
    sbase[tid] = (int)floorf(mn) - 2;
  }
  __syncthreads();
  for (int s = tid; s < AANG*28; s += 256){
    int a = s / 28, j = s - a*28;
    int idx = sbase[a] + j;
    sh[s] = (idx >= 0 && idx < DDET) ? h1[a*DDET + idx] : 0.f;
  }
  __syncthreads();
  int x = x0 + (tid & 15), y = y0 + (tid >> 4);
  float X = (float)x - 255.5f, Y = (float)y - 255.5f;
  float acc = 0.f;
  #pragma unroll 6
  for (int a=0;a<AANG;a++){
    float sidx = fmaf(X, strig[a], fmaf(Y, strig[AANG+a], 364.0f));
    float ff = floorf(sidx);
    int k = (int)ff - sbase[a];
    float fi = sidx - ff;
    float v0 = sh[a*28+k], v1 = sh[a*28+k+1];
    acc += v0 + fi*(v1-v0);
  }
  out[y*SS+x] = acc;
}

// ---------------- dual-space 3x3 conv: 1 px/thread, scalar FMA (R2-proven) ----------------
template<int COUT, int W>
__global__ __launch_bounds__(256) void conv3x3_fast(
    const float* __restrict__ in1, int Cin1,
    const float* __restrict__ in2, int Cin2,
    const float* __restrict__ wt,
    const float* __restrict__ bias, const float* __restrict__ prelu,
    float* __restrict__ out, int H, int accum)
{
  int HW = H*W;
  int pix = blockIdx.x*256 + (int)threadIdx.x;
  if (pix >= HW) return;
  int y = pix / W, x = pix - y*W;
  bool ym = y>0, yp = y<H-1, xm = x>0, xp = x<W-1;
  float acc[COUT];
  #pragma unroll
  for (int o=0;o<COUT;o++) acc[o] = bias[o];
  const float* wr = wt;
  for (int part=0; part<2; part++){
    const float* src = part ? in2 : in1;
    int nch = part ? Cin2 : Cin1;
    const float* ip = src + pix;
    for (int i=0;i<nch;i++, ip+=HW){
      float p4 = ip[0];
      float p0=0,p1=0,p2=0,p3=0,p5=0,p6=0,p7=0,p8=0;
      if (ym){ p1 = ip[-W]; if (xm) p0 = ip[-W-1]; if (xp) p2 = ip[-W+1]; }
      if (xm) p3 = ip[-1];
      if (xp) p5 = ip[1];
      if (yp){ p7 = ip[W]; if (xm) p6 = ip[W-1]; if (xp) p8 = ip[W+1]; }
      float p[9] = {p0,p1,p2,p3,p4,p5,p6,p7,p8};
      #pragma unroll
      for (int t=0;t<9;t++){
        float v = p[t];
        #pragma unroll
        for (int o=0;o<COUT;o++) acc[o] = fmaf(v, wr[t*COUT+o], acc[o]);
      }
      wr += 9*COUT;
    }
  }
  float aa = prelu ? *prelu : 0.f;
  float* op = out + pix;
  #pragma unroll
  for (int o=0;o<COUT;o++){
    float s = acc[o];
    if (prelu) s = (s>=0.f) ? s : aa*s;
    if (accum) s += op[o*HW];
    op[o*HW] = s;
  }
}

// ---------------- primal 3x3 conv: one row per block, 2 px/thread ----------------
// Per input channel: 3 unaligned dwordx4 loads (rows y-1,y,y+1, cols x0-1..x0+2)
// feed 2*9*COUT scalar FMAs. Weights [i][t][COUT] -> wide uniform s_loads per tap.
// Row-stripe XCD swizzle: y = (b&7)*64 + (b>>3).
template<int COUT>
__global__ __launch_bounds__(256) void conv3x3_duo(
    const float* __restrict__ in1, int Cin1,
    const float* __restrict__ in2, int Cin2,
    const float* __restrict__ wt,
    const float* __restrict__ bias, const float* __restrict__ prelu,
    float* __restrict__ out, int accum,
    float* __restrict__ fout, float* __restrict__ tout)
{
  const int W = SS, HW = NPIX;
  int b = blockIdx.x;
  int y = ((b & 7) << 6) | (b >> 3);      // row-stripe per XCD
  int x0 = (int)threadIdx.x * 2;
  int pix0 = y*W + x0;
  bool ym = y > 0, yp = y < SS-1;         // block-uniform
  bool l0 = x0 > 0;                        // false only for thread 0
  bool r3 = x0 + 2 < W;                    // false only for thread 255
  float acc0[COUT], acc1[COUT];
  #pragma unroll
  for (int o=0;o<COUT;o++){ float bv = bias[o]; acc0[o]=bv; acc1[o]=bv; }
  const float* wr = wt;
  for (int part=0; part<2; part++){
    const float* src = part ? in2 : in1;
    int nch = part ? Cin2 : Cin1;
    const float* ip = src + pix0;
    #pragma unroll 2
    for (int i=0;i<nch;i++, ip+=HW){
      v4u A = ym ? *(const v4u*)(ip - W - 1) : (v4u)0.f;
      v4u B = *(const v4u*)(ip - 1);
      v4u D = yp ? *(const v4u*)(ip + W - 1) : (v4u)0.f;
      if (!l0){ A.x = 0.f; B.x = 0.f; D.x = 0.f; }
      if (!r3){ A.w = 0.f; B.w = 0.f; D.w = 0.f; }
      float w0[9] = {A.x,A.y,A.z, B.x,B.y,B.z, D.x,D.y,D.z};
      float w1[9] = {A.y,A.z,A.w, B.y,B.z,B.w, D.y,D.z,D.w};
      #pragma unroll
      for (int t=0;t<9;t++){
        float v0 = w0[t], v1 = w1[t];
        #pragma unroll
        for (int o=0;o<COUT;o++){
          float w = wr[t*COUT+o];
          acc0[o] = fmaf(v0, w, acc0[o]);
          acc1[o] = fmaf(v1, w, acc1[o]);
        }
      }
      wr += 9*COUT;
    }
  }
  float aa = prelu ? *prelu : 0.f;
  float* op = out + pix0;
  #pragma unroll
  for (int o=0;o<COUT;o++){
    float s0 = acc0[o], s1 = acc1[o];
    if (prelu){
      s0 = (s0>=0.f) ? s0 : aa*s0;
      s1 = (s1>=0.f) ? s1 : aa*s1;
    }
    if (accum){
      v2u old = *(const v2u*)(op + o*HW);
      s0 += old.x; s1 += old.y;
    }
    v2u st; st.x = s0; st.y = s1;
    *(v2u*)(op + o*HW) = st;
    if (COUT==5 && o==1 && tout){ tout[x0*SS + y] = s0; tout[(x0+1)*SS + y] = s1; }
    if (COUT==5 && o==0 && fout){
      *(v2u*)(fout + pix0) = st;
      *(v2u*)(fout + HW + pix0) = st;
      *(v2u*)(fout + 2*HW + pix0) = st;
    }
  }
}

extern "C" void kernel_launch(void* const* d_in, const int* in_sizes, int n_in,
                              void* d_out, int out_size, void* d_ws, size_t ws_size,
                              hipStream_t stream){
  const float* g     = (const float*)d_in[2];
  const float* theta = (const float*)d_in[3];
  const float* dw1 = (const float*)d_in[5];
  const float* db1 = (const float*)d_in[6];
  const float* da1 = (const float*)d_in[7];
  const float* dw2 = (const float*)d_in[8];
  const float* db2 = (const float*)d_in[9];
  const float* da2 = (const float*)d_in[10];
  const float* dw3 = (const float*)d_in[11];
  const float* db3 = (const float*)d_in[12];
  const float* pw1 = (const float*)d_in[13];
  const float* pb1 = (const float*)d_in[14];
  const float* pa1 = (const float*)d_in[15];
  const float* pw2 = (const float*)d_in[16];
  const float* pb2 = (const float*)d_in[17];
  const float* pa2 = (const float*)d_in[18];
  const float* pw3 = (const float*)d_in[19];
  const float* pb3 = (const float*)d_in[20];

  float* ws     = (float*)d_ws;
  float* trig   = ws;                  // 128
  float* taps   = ws + 128;            // 1457 (region to 2048)
  float* h      = ws + 2048;           // 5*NSIN
  float* f      = h + 5*NSIN;          // 5*NPIX
  float* imgT   = f + 5*NPIX;          // NPIX  (transpose of f[ch1])
  float* bp     = imgT + NPIX;         // NPIX
  float* dx     = bp + NPIX;           // 2*NSIN  (opf | g copy, contiguous)
  float* opf    = dx;
  float* gcopy  = dx + NSIN;
  float* h1     = dx + 2*NSIN;         // NSIN
  float* primT1 = h1 + NSIN;           // 32*NPIX
  float* primT2 = primT1 + 32*NPIX;    // 32*NPIX
  float* dualT1 = primT1;              // aliased, lifetimes disjoint
  float* dualT2 = dualT1 + 32*NSIN;
  float* wsp  = primT2 + 32*NPIX;
  float* wtd1 = wsp;                   // 20160
  float* wtd2 = wsp + 20160;           // 92160
  float* wtd3 = wsp + 112320;          // 14400
  float* wtp1 = wsp + 126720;          // 17280
  float* wtp2 = wsp + 144000;          // 92160
  float* wtp3 = wsp + 236160;          // 14400

  // zero h, f, imgT (contiguous)
  hipMemsetAsync(h, 0, (size_t)(5*NSIN + 5*NPIX + NPIX)*sizeof(float), stream);
  hipMemcpyAsync(gcopy, g, (size_t)NSIN*sizeof(float), hipMemcpyDeviceToDevice, stream);
  trig_kernel<<<1,64,0,stream>>>(theta, trig);
  taps_kernel<<<NTAPS,256,0,stream>>>(taps);
  transpose_all<<<(250560+255)/256,256,0,stream>>>(dw1,wtd1, dw2,wtd2, dw3,wtd3,
                                                   pw1,wtp1, pw2,wtp2, pw3,wtp3);

  const int GD = (NSIN+255)/256;   // 171

  for (int i=0;i<10;i++){
    radon_fwd_kernel<<<(NSIN+3)/4,256,0,stream>>>(f + NPIX, imgT, trig, opf);
    // dual block: in = [h(5) | opf(1) g(1)]
    conv3x3_fast<32,DDET><<<GD,256,0,stream>>>(h, 5, dx, 2,           wtd1+i*7*9*32,  db1+(size_t)i*32, da1+i, dualT1, AANG, 0);
    conv3x3_fast<32,DDET><<<GD,256,0,stream>>>(dualT1, 32, nullptr, 0, wtd2+i*32*9*32, db2+(size_t)i*32, da2+i, dualT2, AANG, 0);
    conv3x3_fast<5,DDET><<<GD,256,0,stream>>>(dualT2, 32, nullptr, 0,  wtd3+i*32*9*5,  db3+(size_t)i*5,  nullptr, h, AANG, 1);
    filter_kernel<<<GD,256,0,stream>>>(h, taps, h1);
    backproj_kernel<<<NPIX/256,256,0,stream>>>(h1, trig, bp);
    // primal block: in = [f(5) | bp(1)]
    conv3x3_duo<32><<<SS,256,0,stream>>>(f, 5, bp, 1,            wtp1+i*6*9*32,  pb1+(size_t)i*32, pa1+i, primT1, 0, nullptr, nullptr);
    conv3x3_duo<32><<<SS,256,0,stream>>>(primT1, 32, nullptr, 0, wtp2+i*32*9*32, pb2+(size_t)i*32, pa2+i, primT2, 0, nullptr, nullptr);
    conv3x3_duo<5><<<SS,256,0,stream>>>(primT2, 32, nullptr, 0,  wtp3+i*32*9*5,  pb3+(size_t)i*5,  nullptr, f, 1,
                                        (i==9) ? (float*)d_out : nullptr, imgT);
  }
}

// Round 5
// 2927.826 us; speedup vs baseline: 1.1839x; 1.0541x over previous
//
#include <hip/hip_runtime.h>
#include <math.h>

#define SS 512
#define AANG 60
#define DDET 729
#define NPIX (SS*SS)        // 262144
#define NSIN (AANG*DDET)    // 43740
#define NTAPS 1457

typedef float v4u __attribute__((ext_vector_type(4), aligned(4)));
typedef float v4a __attribute__((ext_vector_type(4), aligned(16)));
typedef float v2u __attribute__((ext_vector_type(2), aligned(8)));
typedef float v2a __attribute__((ext_vector_type(2), aligned(4)));

// ---------------- trig table: ca[60], sa[60] ----------------
__global__ void trig_kernel(const float* __restrict__ theta, float* __restrict__ trig){
  int a = threadIdx.x;
  if (a < AANG){ trig[a] = cosf(theta[a]); trig[AANG+a] = sinf(theta[a]); }
}

// ---------------- ramp-filter taps (exact irfft of 2*rfftfreq(2048), folded pi/120) --------
__global__ void taps_kernel(float* __restrict__ taps){
  __shared__ double red[256];
  int m  = blockIdx.x;      // 0..1456
  int mm = m - 728;         // -728..728
  double s = 0.0;
  for (int k = 1 + (int)threadIdx.x; k <= 1023; k += 256){
    int phase = (k*mm) & 2047;   // exact integer mod 2048 (works for negative)
    s += (double)k * cos((double)phase * (M_PI/1024.0));
  }
  red[threadIdx.x] = s;
  __syncthreads();
  for (int off=128; off; off>>=1){
    if ((int)threadIdx.x < off) red[threadIdx.x] += red[threadIdx.x+off];
    __syncthreads();
  }
  if (threadIdx.x==0){
    double x = (red[0]*(1.0/512.0) + ((mm & 1) ? -1.0 : 1.0)) / 2048.0;
    taps[m] = (float)(x * (M_PI/120.0));   // fold FBP normalization pi/(2*60)
  }
}

// ---------------- all six weight transposes in ONE dispatch ----------------
// [L][Cout][Cin][3][3] -> [L][Cin][9][Cout]
__global__ void transpose_all(const float* __restrict__ s0, float* __restrict__ d0,
                              const float* __restrict__ s1, float* __restrict__ d1,
                              const float* __restrict__ s2, float* __restrict__ d2,
                              const float* __restrict__ s3, float* __restrict__ d3,
                              const float* __restrict__ s4, float* __restrict__ d4,
                              const float* __restrict__ s5, float* __restrict__ d5){
  int idx = blockIdx.x*256 + (int)threadIdx.x;
  const float* src; float* dst; int Cout, Cin;
  if      (idx < 20160){                src=s0; dst=d0; Cout=32; Cin=7; }
  else if (idx < 112320){ idx-=20160;   src=s1; dst=d1; Cout=32; Cin=32; }
  else if (idx < 126720){ idx-=112320;  src=s2; dst=d2; Cout=5;  Cin=32; }
  else if (idx < 144000){ idx-=126720;  src=s3; dst=d3; Cout=32; Cin=6; }
  else if (idx < 236160){ idx-=144000;  src=s4; dst=d4; Cout=32; Cin=32; }
  else if (idx < 250560){ idx-=236160;  src=s5; dst=d5; Cout=5;  Cin=32; }
  else return;
  int t = idx % 9; int r = idx/9;
  int i = r % Cin; r /= Cin;
  int o = r % Cout; int l = r/Cout;
  dst[((l*Cin+i)*9+t)*Cout+o] = src[idx];
}

// ---------------- weight re-layout for oct conv: [L][O=32][Cin][3][3] -> [L][Cin][cg=4][t=9][u=8] --
__global__ void transpose_w8(const float* __restrict__ src, float* __restrict__ dst, int Cin){
  int idx = blockIdx.x*256 + (int)threadIdx.x;
  int tot = 10*32*Cin*9;
  if (idx >= tot) return;
  int t = idx % 9; int r = idx/9;
  int i = r % Cin; r /= Cin;
  int o = r % 32; int l = r/32;
  int cg = o >> 3, u = o & 7;
  dst[(((l*Cin + i)*4 + cg)*9 + t)*8 + u] = src[idx];
}

// ---------------- radon forward with support clipping + transpose choice ----------------
__device__ inline void clipr(float al, float be, float lo, float hi,
                             float& A, float& B, bool& empty){
  if (fabsf(al) < 1e-7f){ if (be < lo || be > hi) empty = true; return; }
  float t0 = (lo - be)/al, t1 = (hi - be)/al;
  float mn = fminf(t0,t1), mx = fmaxf(t0,t1);
  A = fmaxf(A, mn); B = fminf(B, mx);
}

__device__ inline float samp_guard(const float* __restrict__ base, float aR, float bR,
                                   float aC, float bC, int t){
  float tp = (float)t - 255.5f;
  float R = fmaf(aR, tp, bR);
  float C = fmaf(aC, tp, bC);
  float rf = floorf(R), cf = floorf(C);
  int r0 = (int)rf, c0 = (int)cf;
  int r1 = r0+1,    c1 = c0+1;
  float fr = R - rf, fc = C - cf;
  bool r0ok = (r0>=0 && r0<SS), r1ok = (r1>=0 && r1<SS);
  bool c0ok = (c0>=0 && c0<SS), c1ok = (c1>=0 && c1<SS);
  float v00 = (r0ok && c0ok) ? base[r0*SS+c0] : 0.f;
  float v01 = (r0ok && c1ok) ? base[r0*SS+c1] : 0.f;
  float v10 = (r1ok && c0ok) ? base[r1*SS+c0] : 0.f;
  float v11 = (r1ok && c1ok) ? base[r1*SS+c1] : 0.f;
  return (1.f-fr)*((1.f-fc)*v00 + fc*v01) + fr*((1.f-fc)*v10 + fc*v11);
}

__global__ __launch_bounds__(256) void radon_fwd_kernel(
    const float* __restrict__ img, const float* __restrict__ imgT,
    const float* __restrict__ trig, float* __restrict__ out){
  int gid  = blockIdx.x*4 + ((int)threadIdx.x >> 6);
  int lane = (int)threadIdx.x & 63;
  if (gid >= NSIN) return;
  int a = gid / DDET;
  int d = gid - a*DDET;
  float ca = trig[a], sa = trig[AANG+a];
  float sd = (float)d - 364.0f;
  float Rc = fmaf(sd, sa, 255.5f);
  float Cc = fmaf(sd, ca, 255.5f);
  float aR = ca, bR = Rc, aC = -sa, bC = Cc;
  const float* base = img;
  if (fabsf(ca) > fabsf(sa)){
    base = imgT;
    float tmp;
    tmp=aR; aR=aC; aC=tmp;
    tmp=bR; bR=bC; bC=tmp;
  }
  float tiA = -255.5f, tiB = 255.5f;  bool iE=false;
  float teA = -255.5f, teB = 255.5f;  bool eE=false;
  clipr(aR,bR, 0.001f, 510.999f, tiA,tiB,iE);
  clipr(aC,bC, 0.001f, 510.999f, tiA,tiB,iE);
  clipr(aR,bR, -0.999f, 511.999f, teA,teB,eE);
  clipr(aC,bC, -0.999f, 511.999f, teA,teB,eE);
  float acc = 0.f;
  if (!eE && teA <= teB){
    int eA = max(0,   (int)floorf(teA+255.5f) - 1);
    int eB = min(511, (int)ceilf (teB+255.5f) + 1);
    int iA = (int)ceilf (tiA+255.5f) + 1;
    int iB = (int)floorf(tiB+255.5f) - 1;
    iA = max(iA, eA); iB = min(iB, eB);
    if (iE || iA > iB){
      for (int t = eA+lane; t <= eB; t += 64) acc += samp_guard(base,aR,bR,aC,bC,t);
    } else {
      for (int t = eA+lane;   t <  iA; t += 64) acc += samp_guard(base,aR,bR,aC,bC,t);
      for (int t = iB+1+lane; t <= eB; t += 64) acc += samp_guard(base,aR,bR,aC,bC,t);
      for (int t = iA+lane;   t <= iB; t += 64){
        float tp = (float)t - 255.5f;
        float R = fmaf(aR, tp, bR);
        float C = fmaf(aC, tp, bC);
        int r0 = (int)R, c0 = (int)C;
        float fr = R - (float)r0, fc = C - (float)c0;
        const float* p = base + r0*SS + c0;
        float v00 = p[0], v01 = p[1], v10 = p[SS], v11 = p[SS+1];
        float top = v00 + fc*(v01-v00);
        float bot = v10 + fc*(v11-v10);
        acc += top + fr*(bot-top);
      }
    }
  }
  for (int off=32; off; off>>=1) acc += __shfl_down(acc, off);
  if (lane==0) out[gid] = acc;
}

// ---------------- ramp filter: direct 1457-tap conv along detector axis ----------------
__global__ void filter_kernel(const float* __restrict__ h0, const float* __restrict__ taps,
                              float* __restrict__ h1){
  int gid = blockIdx.x*blockDim.x + threadIdx.x;
  if (gid >= NSIN) return;
  int a = gid / DDET;
  int j = gid - a*DDET;
  const float* row = h0 + a*DDET;
  float acc = 0.f;
  for (int k=0;k<DDET;k++){
    acc += row[k] * taps[728 + j - k];
  }
  h1[gid] = acc;
}

// ---------------- backprojection with LDS-staged detector windows ----------------
__global__ __launch_bounds__(256) void backproj_kernel(
    const float* __restrict__ h1, const float* __restrict__ trig,
    float* __restrict__ out){
  __shared__ float sh[AANG*28];
  __shared__ int   sbase[AANG];
  __shared__ float strig[2*AANG];
  int tid = threadIdx.x;
  int x0 = (blockIdx.x & 31) * 16, y0 = (blockIdx.x >> 5) * 16;
  if (tid < 2*AANG) strig[tid] = trig[tid];
  __syncthreads();
  if (tid < AANG){
    float ca = strig[tid], sa = strig[AANG+tid];
    float Xa = (float)x0 - 255.5f, Xb = Xa + 15.f;
    float Ya = (float)y0 - 255.5f, Yb = Ya + 15.f;
    float s00 = Xa*ca + Ya*sa, s01 = Xb*ca + Ya*sa;
    float s10 = Xa*ca + Yb*sa, s11 = Xb*ca + Yb*sa;
    float mn = fminf(fminf(s00,s01), fminf(s10,s11)) + 364.0f;
    sbase[tid] = (int)floorf(mn) - 2;
  }
  __syncthreads();
  for (int s = tid; s < AANG*28; s += 256){
    int a = s / 28, j = s - a*28;
    int idx = sbase[a] + j;
    sh[s] = (idx >= 0 && idx < DDET) ? h1[a*DDET + idx] : 0.f;
  }
  __syncthreads();
  int x = x0 + (tid & 15), y = y0 + (tid >> 4);
  float X = (float)x - 255.5f, Y = (float)y - 255.5f;
  float acc = 0.f;
  #pragma unroll 6
  for (int a=0;a<AANG;a++){
    float sidx = fmaf(X, strig[a], fmaf(Y, strig[AANG+a], 364.0f));
    float ff = floorf(sidx);
    int k = (int)ff - sbase[a];
    float fi = sidx - ff;
    float v0 = sh[a*28+k], v1 = sh[a*28+k+1];
    acc += v0 + fi*(v1-v0);
  }
  out[y*SS+x] = acc;
}

// ---------------- dual-space 3x3 conv: 1 px/thread, scalar FMA (R2-proven) ----------------
template<int COUT, int W>
__global__ __launch_bounds__(256) void conv3x3_fast(
    const float* __restrict__ in1, int Cin1,
    const float* __restrict__ in2, int Cin2,
    const float* __restrict__ wt,
    const float* __restrict__ bias, const float* __restrict__ prelu,
    float* __restrict__ out, int H, int accum)
{
  int HW = H*W;
  int pix = blockIdx.x*256 + (int)threadIdx.x;
  if (pix >= HW) return;
  int y = pix / W, x = pix - y*W;
  bool ym = y>0, yp = y<H-1, xm = x>0, xp = x<W-1;
  float acc[COUT];
  #pragma unroll
  for (int o=0;o<COUT;o++) acc[o] = bias[o];
  const float* wr = wt;
  for (int part=0; part<2; part++){
    const float* src = part ? in2 : in1;
    int nch = part ? Cin2 : Cin1;
    const float* ip = src + pix;
    for (int i=0;i<nch;i++, ip+=HW){
      float p4 = ip[0];
      float p0=0,p1=0,p2=0,p3=0,p5=0,p6=0,p7=0,p8=0;
      if (ym){ p1 = ip[-W]; if (xm) p0 = ip[-W-1]; if (xp) p2 = ip[-W+1]; }
      if (xm) p3 = ip[-1];
      if (xp) p5 = ip[1];
      if (yp){ p7 = ip[W]; if (xm) p6 = ip[W-1]; if (xp) p8 = ip[W+1]; }
      float p[9] = {p0,p1,p2,p3,p4,p5,p6,p7,p8};
      #pragma unroll
      for (int t=0;t<9;t++){
        float v = p[t];
        #pragma unroll
        for (int o=0;o<COUT;o++) acc[o] = fmaf(v, wr[t*COUT+o], acc[o]);
      }
      wr += 9*COUT;
    }
  }
  float aa = prelu ? *prelu : 0.f;
  float* op = out + pix;
  #pragma unroll
  for (int o=0;o<COUT;o++){
    float s = acc[o];
    if (prelu) s = (s>=0.f) ? s : aa*s;
    if (accum) s += op[o*HW];
    op[o*HW] = s;
  }
}

// ---------------- primal 3x3 conv, register-blocked: 8 px strip x 8 couts per thread ----------
// grid = (128 row-quads, 4 cout-groups). Wave = one image row (64 strips of 8).
// Per input channel: 9 VMEM (30 px floats) + 72 weight floats (contiguous s_load
// bursts, layout [cin][cg][9][8]) -> 576 FMAs. 8 FMAs per weight float.
__device__ inline void loadrow10(float* R, const float* p, bool valid, bool lE, bool rE){
  if (valid){
    v4u a = *(const v4u*)(p-1);
    v4u b = *(const v4u*)(p+3);
    v2a c = *(const v2a*)(p+7);
    R[0]=lE?0.f:a.x; R[1]=a.y; R[2]=a.z; R[3]=a.w;
    R[4]=b.x; R[5]=b.y; R[6]=b.z; R[7]=b.w;
    R[8]=c.x; R[9]=rE?0.f:c.y;
  } else {
    #pragma unroll
    for (int k=0;k<10;k++) R[k]=0.f;
  }
}

__global__ __launch_bounds__(256) void conv3x3_oct(
    const float* __restrict__ in1, int Cin1,
    const float* __restrict__ in2, int Cin2,
    const float* __restrict__ wt,   // this layer: [cin][4][9][8]
    const float* __restrict__ bias, const float* __restrict__ prelu,
    float* __restrict__ out)
{
  const int W = SS, HW = NPIX;
  int rb = blockIdx.x;                     // 0..127
  int cg = blockIdx.y;                     // 0..3
  int yb = ((rb & 7) << 4) | (rb >> 3);    // XCD swizzle over row-quads
  int wv = (int)threadIdx.x >> 6;
  int lane = (int)threadIdx.x & 63;
  int y = yb*4 + wv;
  int xb = lane*8;
  const float* wch = wt + cg*72;           // advance 288 per input channel
  float acc[8][8];
  #pragma unroll
  for (int px=0;px<8;px++)
    #pragma unroll
    for (int o=0;o<8;o++) acc[px][o] = 0.f;
  bool ym = y>0, yp = y<SS-1;              // wave-uniform
  bool lE = (lane==0), rE = (lane==63);
  for (int part=0; part<2; part++){
    const float* src = part ? in2 : in1;
    int nch = part ? Cin2 : Cin1;
    const float* ip = src + y*W + xb;
    for (int i=0;i<nch;i++, ip+=HW, wch+=288){
      float R[3][10];
      loadrow10(R[0], ip - W, ym,   lE, rE);
      loadrow10(R[1], ip,     true, lE, rE);
      loadrow10(R[2], ip + W, yp,   lE, rE);
      #pragma unroll
      for (int dy=0;dy<3;dy++){
        #pragma unroll
        for (int dx=0;dx<3;dx++){
          #pragma unroll
          for (int o=0;o<8;o++){
            float w = wch[(dy*3+dx)*8+o];
            #pragma unroll
            for (int px=0;px<8;px++)
              acc[px][o] = fmaf(R[dy][px+dx], w, acc[px][o]);
          }
        }
      }
    }
  }
  float aa = prelu ? *prelu : 0.f;
  float* op = out + (size_t)(cg*8)*HW + y*W + xb;
  #pragma unroll
  for (int o=0;o<8;o++){
    float bv = bias[cg*8+o];
    v4a s0, s1;
    s0.x=acc[0][o]+bv; s0.y=acc[1][o]+bv; s0.z=acc[2][o]+bv; s0.w=acc[3][o]+bv;
    s1.x=acc[4][o]+bv; s1.y=acc[5][o]+bv; s1.z=acc[6][o]+bv; s1.w=acc[7][o]+bv;
    s0.x=(s0.x>=0.f)?s0.x:aa*s0.x; s0.y=(s0.y>=0.f)?s0.y:aa*s0.y;
    s0.z=(s0.z>=0.f)?s0.z:aa*s0.z; s0.w=(s0.w>=0.f)?s0.w:aa*s0.w;
    s1.x=(s1.x>=0.f)?s1.x:aa*s1.x; s1.y=(s1.y>=0.f)?s1.y:aa*s1.y;
    s1.z=(s1.z>=0.f)?s1.z:aa*s1.z; s1.w=(s1.w>=0.f)?s1.w:aa*s1.w;
    *(v4a*)(op + o*HW) = s0;
    *(v4a*)(op + o*HW + 4) = s1;
  }
}

// ---------------- primal conv3 (32->5): one row per block, 2 px/thread ----------------
template<int COUT>
__global__ __launch_bounds__(256) void conv3x3_duo(
    const float* __restrict__ in1, int Cin1,
    const float* __restrict__ in2, int Cin2,
    const float* __restrict__ wt,
    const float* __restrict__ bias, const float* __restrict__ prelu,
    float* __restrict__ out, int accum,
    float* __restrict__ fout, float* __restrict__ tout)
{
  const int W = SS, HW = NPIX;
  int b = blockIdx.x;
  int y = ((b & 7) << 6) | (b >> 3);      // row-stripe per XCD
  int x0 = (int)threadIdx.x * 2;
  int pix0 = y*W + x0;
  bool ym = y > 0, yp = y < SS-1;         // block-uniform
  bool l0 = x0 > 0;
  bool r3 = x0 + 2 < W;
  float acc0[COUT], acc1[COUT];
  #pragma unroll
  for (int o=0;o<COUT;o++){ float bv = bias[o]; acc0[o]=bv; acc1[o]=bv; }
  const float* wr = wt;
  for (int part=0; part<2; part++){
    const float* src = part ? in2 : in1;
    int nch = part ? Cin2 : Cin1;
    const float* ip = src + pix0;
    #pragma unroll 2
    for (int i=0;i<nch;i++, ip+=HW){
      v4u A = ym ? *(const v4u*)(ip - W - 1) : (v4u)0.f;
      v4u B = *(const v4u*)(ip - 1);
      v4u D = yp ? *(const v4u*)(ip + W - 1) : (v4u)0.f;
      if (!l0){ A.x = 0.f; B.x = 0.f; D.x = 0.f; }
      if (!r3){ A.w = 0.f; B.w = 0.f; D.w = 0.f; }
      float w0[9] = {A.x,A.y,A.z, B.x,B.y,B.z, D.x,D.y,D.z};
      float w1[9] = {A.y,A.z,A.w, B.y,B.z,B.w, D.y,D.z,D.w};
      #pragma unroll
      for (int t=0;t<9;t++){
        float v0 = w0[t], v1 = w1[t];
        #pragma unroll
        for (int o=0;o<COUT;o++){
          float w = wr[t*COUT+o];
          acc0[o] = fmaf(v0, w, acc0[o]);
          acc1[o] = fmaf(v1, w, acc1[o]);
        }
      }
      wr += 9*COUT;
    }
  }
  float aa = prelu ? *prelu : 0.f;
  float* op = out + pix0;
  #pragma unroll
  for (int o=0;o<COUT;o++){
    float s0 = acc0[o], s1 = acc1[o];
    if (prelu){
      s0 = (s0>=0.f) ? s0 : aa*s0;
      s1 = (s1>=0.f) ? s1 : aa*s1;
    }
    if (accum){
      v2u old = *(const v2u*)(op + o*HW);
      s0 += old.x; s1 += old.y;
    }
    v2u st; st.x = s0; st.y = s1;
    *(v2u*)(op + o*HW) = st;
    if (COUT==5 && o==1 && tout){ tout[x0*SS + y] = s0; tout[(x0+1)*SS + y] = s1; }
    if (COUT==5 && o==0 && fout){
      *(v2u*)(fout + pix0) = st;
      *(v2u*)(fout + HW + pix0) = st;
      *(v2u*)(fout + 2*HW + pix0) = st;
    }
  }
}

extern "C" void kernel_launch(void* const* d_in, const int* in_sizes, int n_in,
                              void* d_out, int out_size, void* d_ws, size_t ws_size,
                              hipStream_t stream){
  const float* g     = (const float*)d_in[2];
  const float* theta = (const float*)d_in[3];
  const float* dw1 = (const float*)d_in[5];
  const float* db1 = (const float*)d_in[6];
  const float* da1 = (const float*)d_in[7];
  const float* dw2 = (const float*)d_in[8];
  const float* db2 = (const float*)d_in[9];
  const float* da2 = (const float*)d_in[10];
  const float* dw3 = (const float*)d_in[11];
  const float* db3 = (const float*)d_in[12];
  const float* pw1 = (const float*)d_in[13];
  const float* pb1 = (const float*)d_in[14];
  const float* pa1 = (const float*)d_in[15];
  const float* pw2 = (const float*)d_in[16];
  const float* pb2 = (const float*)d_in[17];
  const float* pa2 = (const float*)d_in[18];
  const float* pw3 = (const float*)d_in[19];
  const float* pb3 = (const float*)d_in[20];

  float* ws     = (float*)d_ws;
  float* trig   = ws;                  // 128
  float* taps   = ws + 128;            // 1457 (region to 2048)
  float* h      = ws + 2048;           // 5*NSIN
  float* f      = h + 5*NSIN;          // 5*NPIX
  float* imgT   = f + 5*NPIX;          // NPIX  (transpose of f[ch1])
  float* bp     = imgT + NPIX;         // NPIX
  float* dx     = bp + NPIX;           // 2*NSIN  (opf | g copy, contiguous)
  float* opf    = dx;
  float* gcopy  = dx + NSIN;
  float* h1     = dx + 2*NSIN;         // NSIN
  float* primT1 = h1 + NSIN;           // 32*NPIX
  float* primT2 = primT1 + 32*NPIX;    // 32*NPIX
  float* dualT1 = primT1;              // aliased, lifetimes disjoint
  float* dualT2 = dualT1 + 32*NSIN;
  float* wsp   = primT2 + 32*NPIX;
  float* wtd1  = wsp;                  // 20160
  float* wtd2  = wsp + 20160;          // 92160
  float* wtd3  = wsp + 112320;         // 14400
  float* wtp1  = wsp + 126720;         // 17280 (legacy layout, unused by oct)
  float* wtp2  = wsp + 144000;         // 92160 (legacy layout, unused by oct)
  float* wtp3  = wsp + 236160;         // 14400
  float* wtp1b = wsp + 250560;         // 17280  oct layout [l][cin=6][4][9][8]
  float* wtp2b = wsp + 267840;         // 92160  oct layout [l][cin=32][4][9][8]

  // zero h, f, imgT (contiguous)
  hipMemsetAsync(h, 0, (size_t)(5*NSIN + 5*NPIX + NPIX)*sizeof(float), stream);
  hipMemcpyAsync(gcopy, g, (size_t)NSIN*sizeof(float), hipMemcpyDeviceToDevice, stream);
  trig_kernel<<<1,64,0,stream>>>(theta, trig);
  taps_kernel<<<NTAPS,256,0,stream>>>(taps);
  transpose_all<<<(250560+255)/256,256,0,stream>>>(dw1,wtd1, dw2,wtd2, dw3,wtd3,
                                                   pw1,wtp1, pw2,wtp2, pw3,wtp3);
  transpose_w8<<<(17280+255)/256,256,0,stream>>>(pw1, wtp1b, 6);
  transpose_w8<<<(92160+255)/256,256,0,stream>>>(pw2, wtp2b, 32);

  const int GD = (NSIN+255)/256;   // 171

  for (int i=0;i<10;i++){
    radon_fwd_kernel<<<(NSIN+3)/4,256,0,stream>>>(f + NPIX, imgT, trig, opf);
    // dual block: in = [h(5) | opf(1) g(1)]
    conv3x3_fast<32,DDET><<<GD,256,0,stream>>>(h, 5, dx, 2,           wtd1+i*7*9*32,  db1+(size_t)i*32, da1+i, dualT1, AANG, 0);
    conv3x3_fast<32,DDET><<<GD,256,0,stream>>>(dualT1, 32, nullptr, 0, wtd2+i*32*9*32, db2+(size_t)i*32, da2+i, dualT2, AANG, 0);
    conv3x3_fast<5,DDET><<<GD,256,0,stream>>>(dualT2, 32, nullptr, 0,  wtd3+i*32*9*5,  db3+(size_t)i*5,  nullptr, h, AANG, 1);
    filter_kernel<<<GD,256,0,stream>>>(h, taps, h1);
    backproj_kernel<<<NPIX/256,256,0,stream>>>(h1, trig, bp);
    // primal block: in = [f(5) | bp(1)]
    conv3x3_oct<<<dim3(128,4),256,0,stream>>>(f, 5, bp, 1,            wtp1b+(size_t)i*6*288,  pb1+(size_t)i*32, pa1+i, primT1);
    conv3x3_oct<<<dim3(128,4),256,0,stream>>>(primT1, 32, nullptr, 0, wtp2b+(size_t)i*32*288, pb2+(size_t)i*32, pa2+i, primT2);
    conv3x3_duo<5><<<SS,256,0,stream>>>(primT2, 32, nullptr, 0,  wtp3+i*32*9*5,  pb3+(size_t)i*5,  nullptr, f, 1,
                                        (i==9) ? (float*)d_out : nullptr, imgT);
  }
}

// Round 6
// 2423.122 us; speedup vs baseline: 1.4305x; 1.2083x over previous
//
#include <hip/hip_runtime.h>
#include <math.h>

#define SS 512
#define AANG 60
#define DDET 729
#define NPIX (SS*SS)        // 262144
#define NSIN (AANG*DDET)    // 43740
#define NTAPS 1457

typedef float v4u __attribute__((ext_vector_type(4), aligned(4)));
typedef float v4a __attribute__((ext_vector_type(4), aligned(16)));
typedef float v2u __attribute__((ext_vector_type(2), aligned(8)));
typedef float v2a __attribute__((ext_vector_type(2), aligned(4)));

// ---------------- trig table: ca[60], sa[60] ----------------
__global__ void trig_kernel(const float* __restrict__ theta, float* __restrict__ trig){
  int a = threadIdx.x;
  if (a < AANG){ trig[a] = cosf(theta[a]); trig[AANG+a] = sinf(theta[a]); }
}

// ---------------- ramp-filter taps (exact irfft of 2*rfftfreq(2048), folded pi/120) --------
__global__ void taps_kernel(float* __restrict__ taps){
  __shared__ double red[256];
  int m  = blockIdx.x;      // 0..1456
  int mm = m - 728;         // -728..728
  double s = 0.0;
  for (int k = 1 + (int)threadIdx.x; k <= 1023; k += 256){
    int phase = (k*mm) & 2047;   // exact integer mod 2048 (works for negative)
    s += (double)k * cos((double)phase * (M_PI/1024.0));
  }
  red[threadIdx.x] = s;
  __syncthreads();
  for (int off=128; off; off>>=1){
    if ((int)threadIdx.x < off) red[threadIdx.x] += red[threadIdx.x+off];
    __syncthreads();
  }
  if (threadIdx.x==0){
    double x = (red[0]*(1.0/512.0) + ((mm & 1) ? -1.0 : 1.0)) / 2048.0;
    taps[m] = (float)(x * (M_PI/120.0));   // fold FBP normalization pi/(2*60)
  }
}

// ---------------- legacy transposes: [L][Cout][Cin][3][3] -> [L][Cin][9][Cout] (conv3 layers) ----
__global__ void transpose_all(const float* __restrict__ s2, float* __restrict__ d2,
                              const float* __restrict__ s5, float* __restrict__ d5){
  int idx = blockIdx.x*256 + (int)threadIdx.x;
  const float* src; float* dst;
  int Cout = 5, Cin = 32;
  if      (idx < 14400){              src=s2; dst=d2; }
  else if (idx < 28800){ idx-=14400;  src=s5; dst=d5; }
  else return;
  int t = idx % 9; int r = idx/9;
  int i = r % Cin; r /= Cin;
  int o = r % Cout; int l = r/Cout;
  dst[((l*Cin+i)*9+t)*Cout+o] = src[idx];
}

// ---------------- cg-split re-layout: [L][O=32][Cin][3][3] -> [L][Cin][cg=4][t=9][u=8] ----------
__global__ void transpose_w8(const float* __restrict__ src, float* __restrict__ dst, int Cin){
  int idx = blockIdx.x*256 + (int)threadIdx.x;
  int tot = 10*32*Cin*9;
  if (idx >= tot) return;
  int t = idx % 9; int r = idx/9;
  int i = r % Cin; r /= Cin;
  int o = r % 32; int l = r/32;
  int cg = o >> 3, u = o & 7;
  dst[(((l*Cin + i)*4 + cg)*9 + t)*8 + u] = src[idx];
}

// ---------------- radon forward with support clipping + transpose choice ----------------
__device__ inline void clipr(float al, float be, float lo, float hi,
                             float& A, float& B, bool& empty){
  if (fabsf(al) < 1e-7f){ if (be < lo || be > hi) empty = true; return; }
  float t0 = (lo - be)/al, t1 = (hi - be)/al;
  float mn = fminf(t0,t1), mx = fmaxf(t0,t1);
  A = fmaxf(A, mn); B = fminf(B, mx);
}

__device__ inline float samp_guard(const float* __restrict__ base, float aR, float bR,
                                   float aC, float bC, int t){
  float tp = (float)t - 255.5f;
  float R = fmaf(aR, tp, bR);
  float C = fmaf(aC, tp, bC);
  float rf = floorf(R), cf = floorf(C);
  int r0 = (int)rf, c0 = (int)cf;
  int r1 = r0+1,    c1 = c0+1;
  float fr = R - rf, fc = C - cf;
  bool r0ok = (r0>=0 && r0<SS), r1ok = (r1>=0 && r1<SS);
  bool c0ok = (c0>=0 && c0<SS), c1ok = (c1>=0 && c1<SS);
  float v00 = (r0ok && c0ok) ? base[r0*SS+c0] : 0.f;
  float v01 = (r0ok && c1ok) ? base[r0*SS+c1] : 0.f;
  float v10 = (r1ok && c0ok) ? base[r1*SS+c0] : 0.f;
  float v11 = (r1ok && c1ok) ? base[r1*SS+c1] : 0.f;
  return (1.f-fr)*((1.f-fc)*v00 + fc*v01) + fr*((1.f-fc)*v10 + fc*v11);
}

__global__ __launch_bounds__(256) void radon_fwd_kernel(
    const float* __restrict__ img, const float* __restrict__ imgT,
    const float* __restrict__ trig, float* __restrict__ out){
  int gid  = blockIdx.x*4 + ((int)threadIdx.x >> 6);
  int lane = (int)threadIdx.x & 63;
  if (gid >= NSIN) return;
  int a = gid / DDET;
  int d = gid - a*DDET;
  float ca = trig[a], sa = trig[AANG+a];
  float sd = (float)d - 364.0f;
  float Rc = fmaf(sd, sa, 255.5f);
  float Cc = fmaf(sd, ca, 255.5f);
  float aR = ca, bR = Rc, aC = -sa, bC = Cc;
  const float* base = img;
  if (fabsf(ca) > fabsf(sa)){
    base = imgT;
    float tmp;
    tmp=aR; aR=aC; aC=tmp;
    tmp=bR; bR=bC; bC=tmp;
  }
  float tiA = -255.5f, tiB = 255.5f;  bool iE=false;
  float teA = -255.5f, teB = 255.5f;  bool eE=false;
  clipr(aR,bR, 0.001f, 510.999f, tiA,tiB,iE);
  clipr(aC,bC, 0.001f, 510.999f, tiA,tiB,iE);
  clipr(aR,bR, -0.999f, 511.999f, teA,teB,eE);
  clipr(aC,bC, -0.999f, 511.999f, teA,teB,eE);
  float acc = 0.f;
  if (!eE && teA <= teB){
    int eA = max(0,   (int)floorf(teA+255.5f) - 1);
    int eB = min(511, (int)ceilf (teB+255.5f) + 1);
    int iA = (int)ceilf (tiA+255.5f) + 1;
    int iB = (int)floorf(tiB+255.5f) - 1;
    iA = max(iA, eA); iB = min(iB, eB);
    if (iE || iA > iB){
      for (int t = eA+lane; t <= eB; t += 64) acc += samp_guard(base,aR,bR,aC,bC,t);
    } else {
      for (int t = eA+lane;   t <  iA; t += 64) acc += samp_guard(base,aR,bR,aC,bC,t);
      for (int t = iB+1+lane; t <= eB; t += 64) acc += samp_guard(base,aR,bR,aC,bC,t);
      for (int t = iA+lane;   t <= iB; t += 64){
        float tp = (float)t - 255.5f;
        float R = fmaf(aR, tp, bR);
        float C = fmaf(aC, tp, bC);
        int r0 = (int)R, c0 = (int)C;
        float fr = R - (float)r0, fc = C - (float)c0;
        const float* p = base + r0*SS + c0;
        float v00 = p[0], v01 = p[1], v10 = p[SS], v11 = p[SS+1];
        float top = v00 + fc*(v01-v00);
        float bot = v10 + fc*(v11-v10);
        acc += top + fr*(bot-top);
      }
    }
  }
  for (int off=32; off; off>>=1) acc += __shfl_down(acc, off);
  if (lane==0) out[gid] = acc;
}

// ---------------- ramp filter: direct 1457-tap conv along detector axis ----------------
__global__ void filter_kernel(const float* __restrict__ h0, const float* __restrict__ taps,
                              float* __restrict__ h1){
  int gid = blockIdx.x*blockDim.x + threadIdx.x;
  if (gid >= NSIN) return;
  int a = gid / DDET;
  int j = gid - a*DDET;
  const float* row = h0 + a*DDET;
  float acc = 0.f;
  for (int k=0;k<DDET;k++){
    acc += row[k] * taps[728 + j - k];
  }
  h1[gid] = acc;
}

// ---------------- backprojection with LDS-staged detector windows ----------------
__global__ __launch_bounds__(256) void backproj_kernel(
    const float* __restrict__ h1, const float* __restrict__ trig,
    float* __restrict__ out){
  __shared__ float sh[AANG*28];
  __shared__ int   sbase[AANG];
  __shared__ float strig[2*AANG];
  int tid = threadIdx.x;
  int x0 = (blockIdx.x & 31) * 16, y0 = (blockIdx.x >> 5) * 16;
  if (tid < 2*AANG) strig[tid] = trig[tid];
  __syncthreads();
  if (tid < AANG){
    float ca = strig[tid], sa = strig[AANG+tid];
    float Xa = (float)x0 - 255.5f, Xb = Xa + 15.f;
    float Ya = (float)y0 - 255.5f, Yb = Ya + 15.f;
    float s00 = Xa*ca + Ya*sa, s01 = Xb*ca + Ya*sa;
    float s10 = Xa*ca + Yb*sa, s11 = Xb*ca + Yb*sa;
    float mn = fminf(fminf(s00,s01), fminf(s10,s11)) + 364.0f;
    sbase[tid] = (int)floorf(mn) - 2;
  }
  __syncthreads();
  for (int s = tid; s < AANG*28; s += 256){
    int a = s / 28, j = s - a*28;
    int idx = sbase[a] + j;
    sh[s] = (idx >= 0 && idx < DDET) ? h1[a*DDET + idx] : 0.f;
  }
  __syncthreads();
  int x = x0 + (tid & 15), y = y0 + (tid >> 4);
  float X = (float)x - 255.5f, Y = (float)y - 255.5f;
  float acc = 0.f;
  #pragma unroll 6
  for (int a=0;a<AANG;a++){
    float sidx = fmaf(X, strig[a], fmaf(Y, strig[AANG+a], 364.0f));
    float ff = floorf(sidx);
    int k = (int)ff - sbase[a];
    float fi = sidx - ff;
    float v0 = sh[a*28+k], v1 = sh[a*28+k+1];
    acc += v0 + fi*(v1-v0);
  }
  out[y*SS+x] = acc;
}

// ---------------- dual conv, cg-split: 1 px/thread, 8 output channels ----------------
// grid (171, 4); weights [cin][cg=4][9][8]
__global__ __launch_bounds__(256) void conv3x3_dualcg(
    const float* __restrict__ in1, int Cin1,
    const float* __restrict__ in2, int Cin2,
    const float* __restrict__ wt,
    const float* __restrict__ bias, const float* __restrict__ prelu,
    float* __restrict__ out)
{
  const int W = DDET, HW = NSIN;
  int pix = blockIdx.x*256 + (int)threadIdx.x;
  if (pix >= NSIN) return;
  int cg = blockIdx.y;
  int y = pix / W, x = pix - y*W;
  bool ym = y>0, yp = y<AANG-1, xm = x>0, xp = x<W-1;
  float acc[8];
  #pragma unroll
  for (int o=0;o<8;o++) acc[o] = bias[cg*8+o];
  const float* wch = wt + cg*72;
  for (int part=0; part<2; part++){
    const float* src = part ? in2 : in1;
    int nch = part ? Cin2 : Cin1;
    const float* ip = src + pix;
    for (int i=0;i<nch;i++, ip+=HW, wch+=288){
      float p4 = ip[0];
      float p0=0,p1=0,p2=0,p3=0,p5=0,p6=0,p7=0,p8=0;
      if (ym){ p1 = ip[-W]; if (xm) p0 = ip[-W-1]; if (xp) p2 = ip[-W+1]; }
      if (xm) p3 = ip[-1];
      if (xp) p5 = ip[1];
      if (yp){ p7 = ip[W]; if (xm) p6 = ip[W-1]; if (xp) p8 = ip[W+1]; }
      float p[9] = {p0,p1,p2,p3,p4,p5,p6,p7,p8};
      #pragma unroll
      for (int t=0;t<9;t++){
        float v = p[t];
        #pragma unroll
        for (int o=0;o<8;o++) acc[o] = fmaf(v, wch[t*8+o], acc[o]);
      }
    }
  }
  float aa = *prelu;
  float* op = out + (size_t)(cg*8)*HW + pix;
  #pragma unroll
  for (int o=0;o<8;o++){
    float s = acc[o];
    s = (s>=0.f) ? s : aa*s;
    op[o*HW] = s;
  }
}

// ---------------- dual conv3 (32->5): 1 px/thread, accumulate into h ----------------
template<int COUT, int W>
__global__ __launch_bounds__(256) void conv3x3_fast(
    const float* __restrict__ in1, int Cin1,
    const float* __restrict__ wt,
    const float* __restrict__ bias,
    float* __restrict__ out, int H)
{
  int HW = H*W;
  int pix = blockIdx.x*256 + (int)threadIdx.x;
  if (pix >= HW) return;
  int y = pix / W, x = pix - y*W;
  bool ym = y>0, yp = y<H-1, xm = x>0, xp = x<W-1;
  float acc[COUT];
  #pragma unroll
  for (int o=0;o<COUT;o++) acc[o] = bias[o];
  const float* wr = wt;
  const float* ip = in1 + pix;
  for (int i=0;i<Cin1;i++, ip+=HW){
    float p4 = ip[0];
    float p0=0,p1=0,p2=0,p3=0,p5=0,p6=0,p7=0,p8=0;
    if (ym){ p1 = ip[-W]; if (xm) p0 = ip[-W-1]; if (xp) p2 = ip[-W+1]; }
    if (xm) p3 = ip[-1];
    if (xp) p5 = ip[1];
    if (yp){ p7 = ip[W]; if (xm) p6 = ip[W-1]; if (xp) p8 = ip[W+1]; }
    float p[9] = {p0,p1,p2,p3,p4,p5,p6,p7,p8};
    #pragma unroll
    for (int t=0;t<9;t++){
      float v = p[t];
      #pragma unroll
      for (int o=0;o<COUT;o++) acc[o] = fmaf(v, wr[t*COUT+o], acc[o]);
    }
    wr += 9*COUT;
  }
  float* op = out + pix;
  #pragma unroll
  for (int o=0;o<COUT;o++) op[o*HW] += acc[o];
}

// ---------------- primal conv, quad: 4 px x 8 outs per thread, 2 rows/block ----------------
// grid (256, 4) = 1024 blocks -> 4 waves/SIMD. weights [cin][cg=4][9][8].
__device__ inline void loadrow6(float* R, const float* p, bool valid, bool lE, bool rE){
  if (valid){
    v4u a = *(const v4u*)(p-1);
    v2a b = *(const v2a*)(p+3);
    R[0]=lE?0.f:a.x; R[1]=a.y; R[2]=a.z; R[3]=a.w;
    R[4]=b.x; R[5]=rE?0.f:b.y;
  } else {
    #pragma unroll
    for (int k=0;k<6;k++) R[k]=0.f;
  }
}

__global__ __launch_bounds__(256) void conv3x3_quad(
    const float* __restrict__ in1, int Cin1,
    const float* __restrict__ in2, int Cin2,
    const float* __restrict__ wt,
    const float* __restrict__ bias, const float* __restrict__ prelu,
    float* __restrict__ out)
{
  const int W = SS, HW = NPIX;
  int rb = blockIdx.x;                       // 0..255 row-pairs
  int cg = blockIdx.y;                       // 0..3
  int yb = ((rb & 7) << 5) | (rb >> 3);      // XCD swizzle: stripes of 32 row-pairs
  int wv = (int)threadIdx.x >> 6;
  int lane = (int)threadIdx.x & 63;
  int y = yb*2 + (wv >> 1);
  int xb = ((wv & 1) << 8) + lane*4;         // 0..508
  const float* wch = wt + cg*72;             // +288 per input channel
  float acc[4][8];
  #pragma unroll
  for (int px=0;px<4;px++)
    #pragma unroll
    for (int o=0;o<8;o++) acc[px][o] = 0.f;
  bool ym = y>0, yp = y<SS-1;                // wave-uniform
  bool lE = (xb==0), rE = (xb==508);
  for (int part=0; part<2; part++){
    const float* src = part ? in2 : in1;
    int nch = part ? Cin2 : Cin1;
    const float* ip = src + y*W + xb;
    for (int i=0;i<nch;i++, ip+=HW, wch+=288){
      float R[3][6];
      loadrow6(R[0], ip - W, ym,   lE, rE);
      loadrow6(R[1], ip,     true, lE, rE);
      loadrow6(R[2], ip + W, yp,   lE, rE);
      #pragma unroll
      for (int dy=0;dy<3;dy++){
        #pragma unroll
        for (int dx=0;dx<3;dx++){
          #pragma unroll
          for (int o=0;o<8;o++){
            float w = wch[(dy*3+dx)*8+o];
            #pragma unroll
            for (int px=0;px<4;px++)
              acc[px][o] = fmaf(R[dy][px+dx], w, acc[px][o]);
          }
        }
      }
    }
  }
  float aa = *prelu;
  float* op = out + (size_t)(cg*8)*HW + y*W + xb;
  #pragma unroll
  for (int o=0;o<8;o++){
    float bv = bias[cg*8+o];
    v4a s;
    s.x=acc[0][o]+bv; s.y=acc[1][o]+bv; s.z=acc[2][o]+bv; s.w=acc[3][o]+bv;
    s.x=(s.x>=0.f)?s.x:aa*s.x; s.y=(s.y>=0.f)?s.y:aa*s.y;
    s.z=(s.z>=0.f)?s.z:aa*s.z; s.w=(s.w>=0.f)?s.w:aa*s.w;
    *(v4a*)(op + o*HW) = s;
  }
}

// ---------------- primal conv3 (32->5): one row per block, 2 px/thread ----------------
template<int COUT>
__global__ __launch_bounds__(256) void conv3x3_duo(
    const float* __restrict__ in1, int Cin1,
    const float* __restrict__ wt,
    const float* __restrict__ bias,
    float* __restrict__ out,
    float* __restrict__ fout, float* __restrict__ tout)
{
  const int W = SS, HW = NPIX;
  int b = blockIdx.x;
  int y = ((b & 7) << 6) | (b >> 3);      // row-stripe per XCD
  int x0 = (int)threadIdx.x * 2;
  int pix0 = y*W + x0;
  bool ym = y > 0, yp = y < SS-1;         // block-uniform
  bool l0 = x0 > 0;
  bool r3 = x0 + 2 < W;
  float acc0[COUT], acc1[COUT];
  #pragma unroll
  for (int o=0;o<COUT;o++){ float bv = bias[o]; acc0[o]=bv; acc1[o]=bv; }
  const float* wr = wt;
  const float* ip = in1 + pix0;
  #pragma unroll 2
  for (int i=0;i<Cin1;i++, ip+=HW){
    v4u A = ym ? *(const v4u*)(ip - W - 1) : (v4u)0.f;
    v4u B = *(const v4u*)(ip - 1);
    v4u D = yp ? *(const v4u*)(ip + W - 1) : (v4u)0.f;
    if (!l0){ A.x = 0.f; B.x = 0.f; D.x = 0.f; }
    if (!r3){ A.w = 0.f; B.w = 0.f; D.w = 0.f; }
    float w0[9] = {A.x,A.y,A.z, B.x,B.y,B.z, D.x,D.y,D.z};
    float w1[9] = {A.y,A.z,A.w, B.y,B.z,B.w, D.y,D.z,D.w};
    #pragma unroll
    for (int t=0;t<9;t++){
      float v0 = w0[t], v1 = w1[t];
      #pragma unroll
      for (int o=0;o<COUT;o++){
        float w = wr[t*COUT+o];
        acc0[o] = fmaf(v0, w, acc0[o]);
        acc1[o] = fmaf(v1, w, acc1[o]);
      }
    }
    wr += 9*COUT;
  }
  float* op = out + pix0;
  #pragma unroll
  for (int o=0;o<COUT;o++){
    float s0 = acc0[o], s1 = acc1[o];
    v2u old = *(const v2u*)(op + o*HW);
    s0 += old.x; s1 += old.y;
    v2u st; st.x = s0; st.y = s1;
    *(v2u*)(op + o*HW) = st;
    if (o==1 && tout){ tout[x0*SS + y] = s0; tout[(x0+1)*SS + y] = s1; }
    if (o==0 && fout){
      *(v2u*)(fout + pix0) = st;
      *(v2u*)(fout + HW + pix0) = st;
      *(v2u*)(fout + 2*HW + pix0) = st;
    }
  }
}

extern "C" void kernel_launch(void* const* d_in, const int* in_sizes, int n_in,
                              void* d_out, int out_size, void* d_ws, size_t ws_size,
                              hipStream_t stream){
  const float* g     = (const float*)d_in[2];
  const float* theta = (const float*)d_in[3];
  const float* dw1 = (const float*)d_in[5];
  const float* db1 = (const float*)d_in[6];
  const float* da1 = (const float*)d_in[7];
  const float* dw2 = (const float*)d_in[8];
  const float* db2 = (const float*)d_in[9];
  const float* da2 = (const float*)d_in[10];
  const float* dw3 = (const float*)d_in[11];
  const float* db3 = (const float*)d_in[12];
  const float* pw1 = (const float*)d_in[13];
  const float* pb1 = (const float*)d_in[14];
  const float* pa1 = (const float*)d_in[15];
  const float* pw2 = (const float*)d_in[16];
  const float* pb2 = (const float*)d_in[17];
  const float* pa2 = (const float*)d_in[18];
  const float* pw3 = (const float*)d_in[19];
  const float* pb3 = (const float*)d_in[20];

  float* ws     = (float*)d_ws;
  float* trig   = ws;                  // 128
  float* taps   = ws + 128;            // 1457 (region to 2048)
  float* h      = ws + 2048;           // 5*NSIN
  float* f      = h + 5*NSIN;          // 5*NPIX
  float* imgT   = f + 5*NPIX;          // NPIX  (transpose of f[ch1])
  float* bp     = imgT + NPIX;         // NPIX
  float* dx     = bp + NPIX;           // 2*NSIN  (opf | g copy, contiguous)
  float* opf    = dx;
  float* gcopy  = dx + NSIN;
  float* h1     = dx + 2*NSIN;         // NSIN
  float* primT1 = h1 + NSIN;           // 32*NPIX
  float* primT2 = primT1 + 32*NPIX;    // 32*NPIX
  float* dualT1 = primT1;              // aliased, lifetimes disjoint
  float* dualT2 = dualT1 + 32*NSIN;
  float* wsp   = primT2 + 32*NPIX;
  float* wtd3  = wsp;                  // 14400 legacy [cin][9][5]
  float* wtp3  = wsp + 14400;          // 14400 legacy [cin][9][5]
  float* wtd1b = wsp + 28800;          // 20160 cg layout [l][7][4][9][8]
  float* wtd2b = wsp + 48960;          // 92160 cg layout [l][32][4][9][8]
  float* wtp1b = wsp + 141120;         // 17280 cg layout [l][6][4][9][8]
  float* wtp2b = wsp + 158400;         // 92160 cg layout [l][32][4][9][8]

  // zero h, f, imgT (contiguous)
  hipMemsetAsync(h, 0, (size_t)(5*NSIN + 5*NPIX + NPIX)*sizeof(float), stream);
  hipMemcpyAsync(gcopy, g, (size_t)NSIN*sizeof(float), hipMemcpyDeviceToDevice, stream);
  trig_kernel<<<1,64,0,stream>>>(theta, trig);
  taps_kernel<<<NTAPS,256,0,stream>>>(taps);
  transpose_all<<<(28800+255)/256,256,0,stream>>>(dw3,wtd3, pw3,wtp3);
  transpose_w8<<<(20160+255)/256,256,0,stream>>>(dw1, wtd1b, 7);
  transpose_w8<<<(92160+255)/256,256,0,stream>>>(dw2, wtd2b, 32);
  transpose_w8<<<(17280+255)/256,256,0,stream>>>(pw1, wtp1b, 6);
  transpose_w8<<<(92160+255)/256,256,0,stream>>>(pw2, wtp2b, 32);

  const int GD = (NSIN+255)/256;   // 171

  for (int i=0;i<10;i++){
    radon_fwd_kernel<<<(NSIN+3)/4,256,0,stream>>>(f + NPIX, imgT, trig, opf);
    // dual block: in = [h(5) | opf(1) g(1)]
    conv3x3_dualcg<<<dim3(GD,4),256,0,stream>>>(h, 5, dx, 2,           wtd1b+(size_t)i*7*288,  db1+(size_t)i*32, da1+i, dualT1);
    conv3x3_dualcg<<<dim3(GD,4),256,0,stream>>>(dualT1, 32, nullptr, 0, wtd2b+(size_t)i*32*288, db2+(size_t)i*32, da2+i, dualT2);
    conv3x3_fast<5,DDET><<<GD,256,0,stream>>>(dualT2, 32, wtd3+i*32*9*5, db3+(size_t)i*5, h, AANG);
    filter_kernel<<<GD,256,0,stream>>>(h, taps, h1);
    backproj_kernel<<<NPIX/256,256,0,stream>>>(h1, trig, bp);
    // primal block: in = [f(5) | bp(1)]
    conv3x3_quad<<<dim3(256,4),256,0,stream>>>(f, 5, bp, 1,            wtp1b+(size_t)i*6*288,  pb1+(size_t)i*32, pa1+i, primT1);
    conv3x3_quad<<<dim3(256,4),256,0,stream>>>(primT1, 32, nullptr, 0, wtp2b+(size_t)i*32*288, pb2+(size_t)i*32, pa2+i, primT2);
    conv3x3_duo<5><<<SS,256,0,stream>>>(primT2, 32, wtp3+i*32*9*5, pb3+(size_t)i*5, f,
                                        (i==9) ? (float*)d_out : nullptr, imgT);
  }
}